// Round 11
// baseline (184.477 us; speedup 1.0000x reference)
//
#include <hip/hip_runtime.h>
#include <math.h>

#define Tt 1024
#define Dd 1024
#define Hh 16
#define DHh 64
#define MAXPOS 64
#define BTt 2048

typedef short short8 __attribute__((ext_vector_type(8)));
typedef float floatx4 __attribute__((ext_vector_type(4)));

#define MFMA16 __builtin_amdgcn_mfma_f32_16x16x32_bf16

__device__ __forceinline__ unsigned short f2bf(float f) {
    unsigned u;
    __builtin_memcpy(&u, &f, 4);
    u = (u + 0x7FFFu + ((u >> 16) & 1u)) >> 16;
    return (unsigned short)u;
}
__device__ __forceinline__ float bf2fs(short s) {
    unsigned u = ((unsigned)(unsigned short)s) << 16;
    float f;
    __builtin_memcpy(&f, &u, 4);
    return f;
}
// fast sigmoid: v_rcp_f32 instead of IEEE div (~1 ulp; threshold margin is 4x)
__device__ __forceinline__ float fsigm(float x) {
    return __builtin_amdgcn_rcpf(1.f + __expf(-x));
}
// async global->LDS DMA, 16B/lane. LDS dest is wave-uniform base + lane*16;
// global src is per-lane. (m97 staging pattern; compiler never auto-emits this.)
__device__ __forceinline__ void gl2lds16(const short* __restrict__ g, short* l) {
    __builtin_amdgcn_global_load_lds(
        (const __attribute__((address_space(1))) void*)g,
        (__attribute__((address_space(3))) void*)l,
        16, 0, 0);
}

// ---------------- fp32 -> bf16 pre-conversion (x + 4 weights) -------------------
__global__ __launch_bounds__(256) void conv_bf16(
    const float* __restrict__ x,  const float* __restrict__ W0,
    const float* __restrict__ W1, const float* __restrict__ W2,
    const float* __restrict__ W3,
    short* __restrict__ xb, short* __restrict__ w0b, short* __restrict__ w1b,
    short* __restrict__ w2b, short* __restrict__ w3b)
{
    const float* src; short* dst; int n;
    switch (blockIdx.y) {
        case 0:  src = x;  dst = xb;  n = BTt * Dd; break;
        case 1:  src = W0; dst = w0b; n = Dd * Dd;  break;
        case 2:  src = W1; dst = w1b; n = Dd * Dd;  break;
        case 3:  src = W2; dst = w2b; n = Dd * Dd;  break;
        default: src = W3; dst = w3b; n = Dd * Dd;  break;
    }
    int idx = (blockIdx.x * 256 + threadIdx.x) * 8;
    if (idx >= n) return;
    floatx4 a0 = *(const floatx4*)&src[idx];
    floatx4 a1 = *(const floatx4*)&src[idx + 4];
    short8 s;
    for (int e = 0; e < 4; ++e) {
        s[e]     = (short)f2bf(a0[e]);
        s[e + 4] = (short)f2bf(a1[e]);
    }
    *(short8*)&dst[idx] = s;
}

// ------------- MFMA GEMM: C = A[M,K] * W[N,K]^T + bias (bf16 in, bf16 MFMA)
// R16 structure (2-phase dbuf DMA staging) -- the proven-neutral best; frozen.
template <int MODE, int TMW>   // MODE 0: fp32 out, 1: bf16 out
__device__ __forceinline__ void gemm_body(const short* __restrict__ A,
                                          const short* __restrict__ W,
                                          const float* __restrict__ bias,
                                          void* __restrict__ Cout,
                                          int N, int K)
{
    __shared__ __align__(16) short Ash[2][TMW * 64 * 64];
    __shared__ __align__(16) short Bsh[2][64 * 64];
    const int t = threadIdx.x;
    const int lane = t & 63, wave = t >> 6;
    const int quad = lane >> 4, l16 = lane & 15;
    const int row0 = blockIdx.x * (TMW * 64), col0 = blockIdx.y * 64;

    // per-lane source coords within an 8-row DMA stripe
    const int g_r = lane >> 3, g_c = (lane & 7) * 8;

    floatx4 acc[TMW][4];
    for (int a = 0; a < TMW; ++a)
        for (int b2 = 0; b2 < 4; ++b2)
            acc[a][b2] = (floatx4){0.f, 0.f, 0.f, 0.f};

#define STAGE(buf, kb)                                                      \
    do {                                                                    \
        for (int i = 0; i < TMW * 2; ++i) {                                 \
            int rbase = (wave * (TMW * 2) + i) * 8;                         \
            gl2lds16(&A[(size_t)(row0 + rbase + g_r) * K + (kb) + g_c],     \
                     &Ash[buf][rbase * 64]);                                \
        }                                                                   \
        for (int i = 0; i < 2; ++i) {                                       \
            int rbase = (wave * 2 + i) * 8;                                 \
            gl2lds16(&W[(size_t)(col0 + rbase + g_r) * K + (kb) + g_c],     \
                     &Bsh[buf][rbase * 64]);                                \
        }                                                                   \
    } while (0)

    const int NT = K / 64;
    STAGE(0, 0);
    __syncthreads();                       // buf0 ready
    for (int ts = 0; ts < NT; ++ts) {
        const int cur = ts & 1;
        if (ts + 1 < NT) STAGE(cur ^ 1, (ts + 1) * 64);   // async, in flight
        for (int ks = 0; ks < 2; ++ks) {
            short8 af[TMW], bfr[4];
            for (int tm = 0; tm < TMW; ++tm)
                af[tm] = *(short8*)&Ash[cur][(wave * (TMW * 16) + tm * 16 + l16) * 64 + ks * 32 + quad * 8];
            for (int tn = 0; tn < 4; ++tn)
                bfr[tn] = *(short8*)&Bsh[cur][(tn * 16 + l16) * 64 + ks * 32 + quad * 8];
            for (int tm = 0; tm < TMW; ++tm)
                for (int tn = 0; tn < 4; ++tn)
                    acc[tm][tn] = MFMA16(af[tm], bfr[tn], acc[tm][tn], 0, 0, 0);
        }
        if (ts + 1 < NT) __syncthreads();  // next buf ready; recycle fenced
    }
#undef STAGE
    for (int tm = 0; tm < TMW; ++tm)
        for (int tn = 0; tn < 4; ++tn) {
            int col = col0 + tn * 16 + l16;
            float bv = bias[col];
            for (int r = 0; r < 4; ++r) {
                int row = row0 + wave * (TMW * 16) + tm * 16 + quad * 4 + r;
                float v = acc[tm][tn][r] + bv;
                if (MODE == 0) ((float*)Cout)[(size_t)row * N + col] = v;
                else           ((short*)Cout)[(size_t)row * N + col] = (short)f2bf(v);
            }
        }
}

__global__ __launch_bounds__(256) void gemm_qkv(
    const short* __restrict__ xb,
    const short* __restrict__ Wqb, const short* __restrict__ Wkb,
    const short* __restrict__ Wvb,
    const float* __restrict__ bq, const float* __restrict__ bk,
    const float* __restrict__ bv,
    short* __restrict__ Qb, short* __restrict__ Kb, short* __restrict__ Vrow)
{
    if (blockIdx.z == 0)      gemm_body<1, 2>(xb, Wqb, bq, Qb, Dd, Dd);
    else if (blockIdx.z == 1) gemm_body<1, 2>(xb, Wkb, bk, Kb, Dd, Dd);
    else                      gemm_body<1, 2>(xb, Wvb, bv, Vrow, Dd, Dd);
}

__global__ __launch_bounds__(256) void gemm_o(
    const short* __restrict__ A, const short* __restrict__ W,
    const float* __restrict__ bias, float* __restrict__ C)
{
    gemm_body<0, 1>(A, W, bias, C, Dd, Dd);
}

// ---------------- V transpose: Vt[b][d][j] = Vrow[b][j][d], 64x64 tiles ---------
__global__ __launch_bounds__(256) void v_transpose(
    const short* __restrict__ Vrow, short* __restrict__ Vt)
{
    __shared__ __align__(16) short L[64 * 72];
    const int t = threadIdx.x;
    const int j0 = blockIdx.x * 64, d0 = blockIdx.y * 64, b = blockIdx.z;
    for (int s = 0; s < 2; ++s) {
        int c = t * 2 + s;
        int jr = c >> 3, c8 = c & 7;
        *(short8*)&L[jr * 72 + c8 * 8] =
            *(const short8*)&Vrow[((size_t)(b * Tt + j0 + jr)) * Dd + d0 + c8 * 8];
    }
    __syncthreads();
    for (int s = 0; s < 2; ++s) {
        int c = t * 2 + s;
        int dr = c >> 3, c8 = c & 7;
        short8 v;
        for (int e = 0; e < 8; ++e) v[e] = L[(c8 * 8 + e) * 72 + dr];
        *(short8*)&Vt[((size_t)(b * Dd + d0 + dr)) * Tt + j0 + c8 * 8] = v;
    }
}

// CU-balance table: by-quadruples {q,q+8,q+16,q+24} still sum to JT=18 (for the
// 4-resident case), but rows reordered HEAVY-FIRST (JT 8,6 tiles dispatched
// first) so the 2-resident backfill case also ends on a light tail.
__device__ __constant__ int ITMAP[32] = {
    28, 29, 30, 31, 20, 21, 22, 23,
     0,  1,  2,  3,  8,  9, 10, 11,
    24, 25, 26, 27, 16, 17, 18, 19,
     4,  5,  6,  7, 12, 13, 14, 15};

// ---------------- fused attn: scores + no-max softmax + PV (single pass) --------
// R22: SPLIT K/V LDS BUFFERS -> 2 barriers per j-tile (was 4). K and V no
// longer time-share one buffer, so the K-staging write rides inside the C->D
// window: write K(jt-1) right after barrier C (QK^T reads of Kb provably done),
// visible at D (before next tile's QK^T). V write moves after softmax (max T14
// cover), still pre-D. Race audit: Kb w(post-C)/r(post-D) ✓; Vb w(post-C of
// jt-1) vs PV r (pre-C of jt-1) ✓. LDS 39.9 -> 57.2 KB (2 blocks/CU -- R5
// showed 2/CU costs nothing). R14 reverse sweep + T14 early loads kept.
__global__ __launch_bounds__(256) void cope_attn(
    const short* __restrict__ Q, const short* __restrict__ K,
    const short* __restrict__ Vt, const float* __restrict__ PE,
    short* __restrict__ AOb)
{
    const int h = blockIdx.x & 15, b = blockIdx.x >> 4;
    const int it = ITMAP[blockIdx.y];
    const int i0 = it * 32;
    const int t = threadIdx.x, lane = t & 63, wave = t >> 6;
    const int quad = lane >> 4, l16 = lane & 15;

    // SldS: setup Q tile (short) / S tile (f32, row stride 132 floats) /
    //       P tile (bf16, packed, aliased) -- 16.9 KB
    __shared__ __align__(16) short SldS[32 * 264];
    __shared__ __align__(16) short Kbl[128 * 72];   // PE (setup) then K[128][72]
    __shared__ __align__(16) short Vbl[64 * 136];   // V[64][136], dedicated
    __shared__ short qpeB[32 * 68];
    __shared__ float lrow[32];
    float* Sld = (float*)SldS;

    const float inv_scale = 0.125f;
    const int sr = t >> 3, ss = t & 7;
    const int irow = i0 + sr;

    short* QtS = SldS;
    {
        int r = t >> 3, c = t & 7;
        *(short8*)&QtS[r * 72 + c * 8] =
            *(const short8*)&Q[((size_t)(b * Tt + i0 + r)) * Dd + h * DHh + c * 8];
    }
    for (int e = 0; e < 16; ++e) {
        int idx = t + 256 * e;
        int p = idx >> 6, d = idx & 63;
        Kbl[p * 72 + d] = (short)f2bf(PE[((size_t)h * MAXPOS + p) * DHh + d]);
    }
    __syncthreads();

    short8 qa[2][2];
    for (int rb = 0; rb < 2; ++rb)
        for (int ks = 0; ks < 2; ++ks)
            qa[rb][ks] = *(short8*)&QtS[(rb * 16 + l16) * 72 + ks * 32 + quad * 8];

    const int JT = (i0 + 159) >> 7;

    // issue first K prefetch early (hides under qpe MFMA section)
    short8 kreg[4];
    for (int e = 0; e < 4; ++e) {
        int ch = t + 256 * e;
        int jr = ch >> 3, c = ch & 7;
        kreg[e] = *(const short8*)&K[((size_t)(b * Tt + (JT - 1) * 128 + jr)) * Dd + h * DHh + c * 8];
    }

    // qpe table via MFMA (M=32, N=64, K=64), reading PE from Kbl
    {
        int mt = wave >> 1;
        int ntA = 2 * (wave & 1), ntB = ntA + 1;
        floatx4 c0f = {0, 0, 0, 0}, c1f = {0, 0, 0, 0};
        for (int ks = 0; ks < 2; ++ks) {
            short8 b0 = *(short8*)&Kbl[(ntA * 16 + l16) * 72 + ks * 32 + quad * 8];
            short8 b1 = *(short8*)&Kbl[(ntB * 16 + l16) * 72 + ks * 32 + quad * 8];
            c0f = MFMA16(qa[mt][ks], b0, c0f, 0, 0, 0);
            c1f = MFMA16(qa[mt][ks], b1, c1f, 0, 0, 0);
        }
        for (int r = 0; r < 4; ++r) {
            qpeB[(mt * 16 + quad * 4 + r) * 68 + ntA * 16 + l16] = (short)f2bf(c0f[r]);
            qpeB[(mt * 16 + quad * 4 + r) * 68 + ntB * 16 + l16] = (short)f2bf(c1f[r]);
        }
    }
    __syncthreads();          // PE reads done (Kbl free), qpeB visible

    // prologue: stage K(JT-1) into Kbl; prefetch K(JT-2)
    for (int e = 0; e < 4; ++e) {
        int ch = t + 256 * e;
        int jr = ch >> 3, c = ch & 7;
        *(short8*)&Kbl[jr * 72 + c * 8] = kreg[e];
    }
    if (JT > 1) {
        for (int e = 0; e < 4; ++e) {
            int ch = t + 256 * e;
            int jr = ch >> 3, c = ch & 7;
            kreg[e] = *(const short8*)&K[((size_t)(b * Tt + (JT - 2) * 128 + jr)) * Dd + h * DHh + c * 8];
        }
    }
    __syncthreads();          // Kbl holds K(JT-1)

    floatx4 o0 = {0, 0, 0, 0}, o1 = {0, 0, 0, 0};
    const int pv_mt = wave >> 1;
    const int pv_ntA = 2 * (wave & 1), pv_ntB = pv_ntA + 1;
    float l_acc = 0.f;
    float rightAcc = 0.f;     // sum of gates in tiles already processed (k > tile)

    for (int jt = JT - 1; jt >= 0; --jt) {
        const int j0 = jt * 128;
        // T14: issue V-tile loads early (hide under QK^T + C + softmax)
        short8 vreg[4];
        for (int e = 0; e < 4; ++e) {
            int ch = t + 256 * e;
            int d = ch >> 4, c = ch & 15;
            vreg[e] = *(const short8*)&Vt[((size_t)(b * Dd + h * DHh + d)) * Tt + j0 + c * 8];
        }
        // QK^T from Kbl -> S
        {
            int ntA = 2 * wave, ntB = ntA + 1;
            floatx4 c00 = {0,0,0,0}, c01 = {0,0,0,0}, c10 = {0,0,0,0}, c11 = {0,0,0,0};
            for (int ks = 0; ks < 2; ++ks) {
                short8 b0 = *(short8*)&Kbl[(ntA * 16 + l16) * 72 + ks * 32 + quad * 8];
                short8 b1 = *(short8*)&Kbl[(ntB * 16 + l16) * 72 + ks * 32 + quad * 8];
                c00 = MFMA16(qa[0][ks], b0, c00, 0, 0, 0);
                c01 = MFMA16(qa[0][ks], b1, c01, 0, 0, 0);
                c10 = MFMA16(qa[1][ks], b0, c10, 0, 0, 0);
                c11 = MFMA16(qa[1][ks], b1, c11, 0, 0, 0);
            }
            for (int r = 0; r < 4; ++r) {
                Sld[(quad * 4 + r) * 132 + ntA * 16 + l16] = c00[r];
                Sld[(quad * 4 + r) * 132 + ntB * 16 + l16] = c01[r];
                Sld[(16 + quad * 4 + r) * 132 + ntA * 16 + l16] = c10[r];
                Sld[(16 + quad * 4 + r) * 132 + ntB * 16 + l16] = c11[r];
            }
        }
        __syncthreads();                                    // C: S ready; Kbl reads done
        // stage next K into Kbl (visible at D, read next iteration)
        if (jt > 0) {
            for (int e = 0; e < 4; ++e) {
                int ch = t + 256 * e;
                int jr = ch >> 3, c = ch & 7;
                *(short8*)&Kbl[jr * 72 + c * 8] = kreg[e];
            }
            if (jt > 1) {
                for (int e = 0; e < 4; ++e) {
                    int ch = t + 256 * e;
                    int jr = ch >> 3, c = ch & 7;
                    kreg[e] = *(const short8*)&K[((size_t)(b * Tt + j0 - 256 + jr)) * Dd + h * DHh + c * 8];
                }
            }
        }
        {
            // read own 16 S floats (short-typed loads, bit-cast: TBAA-safe alias)
            floatx4 qv[4];
            for (int q4 = 0; q4 < 4; ++q4) {
                short8 qraw = *(short8*)&SldS[sr * 264 + ss * 32 + q4 * 8];
                __builtin_memcpy(&qv[q4], &qraw, 16);
            }
            float gt[16];
            float gs = 0.f;
            for (int e = 0; e < 16; ++e) {
                int j = j0 + ss * 16 + e;
                float qk = qv[e >> 2][e & 3];
                float g = (j <= irow) ? fsigm(qk * inv_scale) : 0.f;
                gt[e] = g;
                gs += g;
            }
            // inclusive suffix-scan of group sums across the 8 ss-groups
            float inc = gs;
            for (int d2 = 1; d2 < 8; d2 <<= 1) {
                float n = __shfl_down(inc, d2, 64);
                if ((lane & 7) + d2 < 8) inc += n;
            }
            // tile-row total lives at ss=0; broadcast within the row group
            float tileTot = __shfl(inc, lane & 56, 64);
            float base = rightAcc + (inc - gs);   // gates strictly right of group
            float run = 0.f;                      // suffix within group (exclusive)
            short8 p0, p1;
            for (int e = 15; e >= 0; --e) {
                int j = j0 + ss * 16 + e;
                float pos = base + run;           // = sum_{k > j} g_k
                run += gt[e];
                pos = fminf(fmaxf(pos, 0.f), 63.f);
                float pf = floorf(pos);
                float al = pos - pf;
                int fi = (int)pf;
                int ci = fi + 1; if (ci > 63) ci = 63;
                float qp = (1.f - al) * bf2fs(qpeB[sr * 68 + fi]) + al * bf2fs(qpeB[sr * 68 + ci]);
                float qk = qv[e >> 2][e & 3];
                float p = (j <= irow) ? __expf((qk + qp) * inv_scale) : 0.f;
                if (e < 8) p0[e] = (short)f2bf(p); else p1[e - 8] = (short)f2bf(p);
                l_acc += p;
            }
            // P overwrites the low half of this thread's OWN consumed S region
            *(short8*)&SldS[sr * 264 + ss * 32]     = p0;
            *(short8*)&SldS[sr * 264 + ss * 32 + 8] = p1;
            rightAcc += tileTot;
        }
        // V write late (vreg landed long ago; max latency cover)
        for (int e = 0; e < 4; ++e) {
            int ch = t + 256 * e;
            int d = ch >> 4, c = ch & 15;
            *(short8*)&Vbl[d * 136 + c * 8] = vreg[e];
        }
        __syncthreads();                                    // D: P + V + nextK visible
        for (int ks = 0; ks < 4; ++ks) {
            short8 a  = *(short8*)&SldS[(pv_mt * 16 + l16) * 264 + ks * 64
                                        + ((quad >> 1) << 5) + ((quad & 1) << 3)];
            short8 b0 = *(short8*)&Vbl[(pv_ntA * 16 + l16) * 136 + ks * 32 + quad * 8];
            short8 b1 = *(short8*)&Vbl[(pv_ntB * 16 + l16) * 136 + ks * 32 + quad * 8];
            o0 = MFMA16(a, b0, o0, 0, 0, 0);
            o1 = MFMA16(a, b1, o1, 0, 0, 0);
        }
    }
    float lr = l_acc;
    for (int d2 = 4; d2 >= 1; d2 >>= 1) lr += __shfl_xor(lr, d2, 64);
    if (ss == 0) lrow[sr] = lr;
    __syncthreads();
    for (int r = 0; r < 4; ++r) {
        int row = pv_mt * 16 + quad * 4 + r;
        float inv = __builtin_amdgcn_rcpf(lrow[row]);
        size_t off = ((size_t)(b * Tt + i0 + row)) * Dd + h * DHh;
        AOb[off + pv_ntA * 16 + l16] = (short)f2bf(o0[r] * inv);
        AOb[off + pv_ntB * 16 + l16] = (short)f2bf(o1[r] * inv);
    }
}

// ---------------- launch ---------------------------------------------------------
extern "C" void kernel_launch(void* const* d_in, const int* in_sizes, int n_in,
                              void* d_out, int out_size, void* d_ws, size_t ws_size,
                              hipStream_t stream)
{
    const float* x  = (const float*)d_in[0];
    const float* Wq = (const float*)d_in[1];
    const float* bq = (const float*)d_in[2];
    const float* Wk = (const float*)d_in[3];
    const float* bk = (const float*)d_in[4];
    const float* Wv = (const float*)d_in[5];
    const float* bv = (const float*)d_in[6];
    const float* Wo = (const float*)d_in[7];
    const float* bo = (const float*)d_in[8];
    const float* pe = (const float*)d_in[9];
    // d_in[10]: causal mask (j > i) — structural, unused

    short* xb   = (short*)d_ws;                         //  4 MB
    short* Wqb  = xb   + (size_t)BTt * Dd;              //  2 MB
    short* Wkb  = Wqb  + (size_t)Dd * Dd;               //  2 MB
    short* Wvb  = Wkb  + (size_t)Dd * Dd;               //  2 MB
    short* Wob  = Wvb  + (size_t)Dd * Dd;               //  2 MB
    short* Qb   = Wob  + (size_t)Dd * Dd;               //  4 MB
    short* Kb   = Qb   + (size_t)BTt * Dd;              //  4 MB
    short* Vrow = Kb   + (size_t)BTt * Dd;              //  4 MB
    short* Vtg  = Vrow + (size_t)BTt * Dd;              //  4 MB
    short* AOb  = Vtg  + (size_t)BTt * Dd;              //  4 MB

    dim3 gc(BTt * Dd / 8 / 256, 5);
    conv_bf16<<<gc, 256, 0, stream>>>(x, Wq, Wk, Wv, Wo, xb, Wqb, Wkb, Wvb, Wob);

    dim3 gq(BTt / 128, Dd / 64, 3);
    gemm_qkv<<<gq, 256, 0, stream>>>(xb, Wqb, Wkb, Wvb, bq, bk, bv, Qb, Kb, Vrow);

    dim3 gv(Tt / 64, Dd / 64, 2);
    v_transpose<<<gv, 256, 0, stream>>>(Vrow, Vtg);

    dim3 ga(32, 32, 1);   // x = h + 16*b; y = itz (CU-balanced via ITMAP)
    cope_attn<<<ga, 256, 0, stream>>>(Qb, Kb, Vtg, pe, AOb);

    dim3 go(BTt / 64, Dd / 64, 1);
    gemm_o<<<go, 256, 0, stream>>>(AOb, Wob, bo, (float*)d_out);
}

// Round 12
// 176.591 us; speedup vs baseline: 1.0447x; 1.0447x over previous
//
#include <hip/hip_runtime.h>
#include <math.h>

#define Tt 1024
#define Dd 1024
#define Hh 16
#define DHh 64
#define MAXPOS 64
#define BTt 2048

typedef short short8 __attribute__((ext_vector_type(8)));
typedef float floatx4 __attribute__((ext_vector_type(4)));

#define MFMA16 __builtin_amdgcn_mfma_f32_16x16x32_bf16

__device__ __forceinline__ unsigned short f2bf(float f) {
    unsigned u;
    __builtin_memcpy(&u, &f, 4);
    u = (u + 0x7FFFu + ((u >> 16) & 1u)) >> 16;
    return (unsigned short)u;
}
__device__ __forceinline__ float bf2fs(short s) {
    unsigned u = ((unsigned)(unsigned short)s) << 16;
    float f;
    __builtin_memcpy(&f, &u, 4);
    return f;
}
// fast sigmoid: v_rcp_f32 instead of IEEE div (~1 ulp; threshold margin is 4x)
__device__ __forceinline__ float fsigm(float x) {
    return __builtin_amdgcn_rcpf(1.f + __expf(-x));
}
// async global->LDS DMA, 16B/lane. LDS dest is wave-uniform base + lane*16;
// global src is per-lane. (m97 staging pattern; compiler never auto-emits this.)
__device__ __forceinline__ void gl2lds16(const short* __restrict__ g, short* l) {
    __builtin_amdgcn_global_load_lds(
        (const __attribute__((address_space(1))) void*)g,
        (__attribute__((address_space(3))) void*)l,
        16, 0, 0);
}

// ---------------- fp32 -> bf16 pre-conversion (x + 4 weights) -------------------
__global__ __launch_bounds__(256) void conv_bf16(
    const float* __restrict__ x,  const float* __restrict__ W0,
    const float* __restrict__ W1, const float* __restrict__ W2,
    const float* __restrict__ W3,
    short* __restrict__ xb, short* __restrict__ w0b, short* __restrict__ w1b,
    short* __restrict__ w2b, short* __restrict__ w3b)
{
    const float* src; short* dst; int n;
    switch (blockIdx.y) {
        case 0:  src = x;  dst = xb;  n = BTt * Dd; break;
        case 1:  src = W0; dst = w0b; n = Dd * Dd;  break;
        case 2:  src = W1; dst = w1b; n = Dd * Dd;  break;
        case 3:  src = W2; dst = w2b; n = Dd * Dd;  break;
        default: src = W3; dst = w3b; n = Dd * Dd;  break;
    }
    int idx = (blockIdx.x * 256 + threadIdx.x) * 8;
    if (idx >= n) return;
    floatx4 a0 = *(const floatx4*)&src[idx];
    floatx4 a1 = *(const floatx4*)&src[idx + 4];
    short8 s;
    for (int e = 0; e < 4; ++e) {
        s[e]     = (short)f2bf(a0[e]);
        s[e + 4] = (short)f2bf(a1[e]);
    }
    *(short8*)&dst[idx] = s;
}

// ------------- MFMA GEMM: C = A[M,K] * W[N,K]^T + bias (bf16 in, bf16 MFMA)
// R16 structure (2-phase dbuf DMA staging) -- the proven-neutral best; frozen.
template <int MODE, int TMW>   // MODE 0: fp32 out, 1: bf16 out
__device__ __forceinline__ void gemm_body(const short* __restrict__ A,
                                          const short* __restrict__ W,
                                          const float* __restrict__ bias,
                                          void* __restrict__ Cout,
                                          int N, int K)
{
    __shared__ __align__(16) short Ash[2][TMW * 64 * 64];
    __shared__ __align__(16) short Bsh[2][64 * 64];
    const int t = threadIdx.x;
    const int lane = t & 63, wave = t >> 6;
    const int quad = lane >> 4, l16 = lane & 15;
    const int row0 = blockIdx.x * (TMW * 64), col0 = blockIdx.y * 64;

    // per-lane source coords within an 8-row DMA stripe
    const int g_r = lane >> 3, g_c = (lane & 7) * 8;

    floatx4 acc[TMW][4];
    for (int a = 0; a < TMW; ++a)
        for (int b2 = 0; b2 < 4; ++b2)
            acc[a][b2] = (floatx4){0.f, 0.f, 0.f, 0.f};

#define STAGE(buf, kb)                                                      \
    do {                                                                    \
        for (int i = 0; i < TMW * 2; ++i) {                                 \
            int rbase = (wave * (TMW * 2) + i) * 8;                         \
            gl2lds16(&A[(size_t)(row0 + rbase + g_r) * K + (kb) + g_c],     \
                     &Ash[buf][rbase * 64]);                                \
        }                                                                   \
        for (int i = 0; i < 2; ++i) {                                       \
            int rbase = (wave * 2 + i) * 8;                                 \
            gl2lds16(&W[(size_t)(col0 + rbase + g_r) * K + (kb) + g_c],     \
                     &Bsh[buf][rbase * 64]);                                \
        }                                                                   \
    } while (0)

    const int NT = K / 64;
    STAGE(0, 0);
    __syncthreads();                       // buf0 ready
    for (int ts = 0; ts < NT; ++ts) {
        const int cur = ts & 1;
        if (ts + 1 < NT) STAGE(cur ^ 1, (ts + 1) * 64);   // async, in flight
        for (int ks = 0; ks < 2; ++ks) {
            short8 af[TMW], bfr[4];
            for (int tm = 0; tm < TMW; ++tm)
                af[tm] = *(short8*)&Ash[cur][(wave * (TMW * 16) + tm * 16 + l16) * 64 + ks * 32 + quad * 8];
            for (int tn = 0; tn < 4; ++tn)
                bfr[tn] = *(short8*)&Bsh[cur][(tn * 16 + l16) * 64 + ks * 32 + quad * 8];
            for (int tm = 0; tm < TMW; ++tm)
                for (int tn = 0; tn < 4; ++tn)
                    acc[tm][tn] = MFMA16(af[tm], bfr[tn], acc[tm][tn], 0, 0, 0);
        }
        if (ts + 1 < NT) __syncthreads();  // next buf ready; recycle fenced
    }
#undef STAGE
    for (int tm = 0; tm < TMW; ++tm)
        for (int tn = 0; tn < 4; ++tn) {
            int col = col0 + tn * 16 + l16;
            float bv = bias[col];
            for (int r = 0; r < 4; ++r) {
                int row = row0 + wave * (TMW * 16) + tm * 16 + quad * 4 + r;
                float v = acc[tm][tn][r] + bv;
                if (MODE == 0) ((float*)Cout)[(size_t)row * N + col] = v;
                else           ((short*)Cout)[(size_t)row * N + col] = (short)f2bf(v);
            }
        }
}

__global__ __launch_bounds__(256) void gemm_qkv(
    const short* __restrict__ xb,
    const short* __restrict__ Wqb, const short* __restrict__ Wkb,
    const short* __restrict__ Wvb,
    const float* __restrict__ bq, const float* __restrict__ bk,
    const float* __restrict__ bv,
    short* __restrict__ Qb, short* __restrict__ Kb, short* __restrict__ Vrow)
{
    if (blockIdx.z == 0)      gemm_body<1, 2>(xb, Wqb, bq, Qb, Dd, Dd);
    else if (blockIdx.z == 1) gemm_body<1, 2>(xb, Wkb, bk, Kb, Dd, Dd);
    else                      gemm_body<1, 2>(xb, Wvb, bv, Vrow, Dd, Dd);
}

__global__ __launch_bounds__(256) void gemm_o(
    const short* __restrict__ A, const short* __restrict__ W,
    const float* __restrict__ bias, float* __restrict__ C)
{
    gemm_body<0, 1>(A, W, bias, C, Dd, Dd);
}

// ---------------- V transpose: Vt[b][d][j] = Vrow[b][j][d], 64x64 tiles ---------
__global__ __launch_bounds__(256) void v_transpose(
    const short* __restrict__ Vrow, short* __restrict__ Vt)
{
    __shared__ __align__(16) short L[64 * 72];
    const int t = threadIdx.x;
    const int j0 = blockIdx.x * 64, d0 = blockIdx.y * 64, b = blockIdx.z;
    for (int s = 0; s < 2; ++s) {
        int c = t * 2 + s;
        int jr = c >> 3, c8 = c & 7;
        *(short8*)&L[jr * 72 + c8 * 8] =
            *(const short8*)&Vrow[((size_t)(b * Tt + j0 + jr)) * Dd + d0 + c8 * 8];
    }
    __syncthreads();
    for (int s = 0; s < 2; ++s) {
        int c = t * 2 + s;
        int dr = c >> 3, c8 = c & 7;
        short8 v;
        for (int e = 0; e < 8; ++e) v[e] = L[(c8 * 8 + e) * 72 + dr];
        *(short8*)&Vt[((size_t)(b * Dd + d0 + dr)) * Tt + j0 + c8 * 8] = v;
    }
}

// CU-balance table (R19, best-measured total): itz -> it such that the 4 blocks
// a CU receives have JT sums 18 -- static balance at 4 blocks/CU with no extra
// j-tile iterations. (R20 work-stealing and R22 barrier-split measured worse;
// both reverted. This file is the best-measured configuration: R19 + T14.)
__device__ __constant__ int ITMAP[32] = {
     0,  1,  2,  3,  8,  9, 10, 11,
    28, 29, 30, 31, 20, 21, 22, 23,
     4,  5,  6,  7, 12, 13, 14, 15,
    24, 25, 26, 27, 16, 17, 18, 19};

// ---------------- fused attn: scores + no-max softmax + PV (single pass) --------
// R23 = R21 (the best-measured cope): R19 base + T14 async-STAGE split. vreg/
// kreg global loads issue right after barrier B so their latency hides under
// QK^T + barrier C + softmax. 4-barrier KV time-share retained -- R22's split
// (2 barriers, 57KB LDS) measured SLOWER: the extra barriers let co-resident
// blocks fill each other's drain windows, and 39.9KB keeps 4 blocks/CU.
__global__ __launch_bounds__(256) void cope_attn(
    const short* __restrict__ Q, const short* __restrict__ K,
    const short* __restrict__ Vt, const float* __restrict__ PE,
    short* __restrict__ AOb)
{
    const int h = blockIdx.x & 15, b = blockIdx.x >> 4;
    const int it = ITMAP[blockIdx.y];
    const int i0 = it * 32;
    const int t = threadIdx.x, lane = t & 63, wave = t >> 6;
    const int quad = lane >> 4, l16 = lane & 15;

    // SldS: setup Q tile (short) / S tile (f32, row stride 132 floats) /
    //       P tile (bf16, packed, aliased) -- 16.9 KB
    __shared__ __align__(16) short SldS[32 * 264];
    __shared__ __align__(16) short KV[128 * 72];    // PE / K[128][72] / V[64][136]
    __shared__ short qpeB[32 * 68];
    __shared__ float lrow[32];
    float* Sld = (float*)SldS;

    const float inv_scale = 0.125f;
    const int sr = t >> 3, ss = t & 7;
    const int irow = i0 + sr;

    short* QtS = SldS;
    {
        int r = t >> 3, c = t & 7;
        *(short8*)&QtS[r * 72 + c * 8] =
            *(const short8*)&Q[((size_t)(b * Tt + i0 + r)) * Dd + h * DHh + c * 8];
    }
    for (int e = 0; e < 16; ++e) {
        int idx = t + 256 * e;
        int p = idx >> 6, d = idx & 63;
        KV[p * 72 + d] = (short)f2bf(PE[((size_t)h * MAXPOS + p) * DHh + d]);
    }
    __syncthreads();

    short8 qa[2][2];
    for (int rb = 0; rb < 2; ++rb)
        for (int ks = 0; ks < 2; ++ks)
            qa[rb][ks] = *(short8*)&QtS[(rb * 16 + l16) * 72 + ks * 32 + quad * 8];

    // qpe table via MFMA (M=32, N=64, K=64)
    {
        int mt = wave >> 1;
        int ntA = 2 * (wave & 1), ntB = ntA + 1;
        floatx4 c0f = {0, 0, 0, 0}, c1f = {0, 0, 0, 0};
        for (int ks = 0; ks < 2; ++ks) {
            short8 b0 = *(short8*)&KV[(ntA * 16 + l16) * 72 + ks * 32 + quad * 8];
            short8 b1 = *(short8*)&KV[(ntB * 16 + l16) * 72 + ks * 32 + quad * 8];
            c0f = MFMA16(qa[mt][ks], b0, c0f, 0, 0, 0);
            c1f = MFMA16(qa[mt][ks], b1, c1f, 0, 0, 0);
        }
        for (int r = 0; r < 4; ++r) {
            qpeB[(mt * 16 + quad * 4 + r) * 68 + ntA * 16 + l16] = (short)f2bf(c0f[r]);
            qpeB[(mt * 16 + quad * 4 + r) * 68 + ntB * 16 + l16] = (short)f2bf(c1f[r]);
        }
    }

    const int JT = (i0 + 159) >> 7;
    floatx4 o0 = {0, 0, 0, 0}, o1 = {0, 0, 0, 0};
    const int pv_mt = wave >> 1;
    const int pv_ntA = 2 * (wave & 1), pv_ntB = pv_ntA + 1;
    float l_acc = 0.f;
    float rightAcc = 0.f;     // sum of gates in tiles already processed (k > tile)

    short8 kreg[4];
    for (int e = 0; e < 4; ++e) {
        int ch = t + 256 * e;
        int jr = ch >> 3, c = ch & 7;
        kreg[e] = *(const short8*)&K[((size_t)(b * Tt + (JT - 1) * 128 + jr)) * Dd + h * DHh + c * 8];
    }

    for (int jt = JT - 1; jt >= 0; --jt) {
        const int j0 = jt * 128;
        __syncthreads();                                    // A: KV free
        for (int e = 0; e < 4; ++e) {
            int ch = t + 256 * e;
            int jr = ch >> 3, c = ch & 7;
            *(short8*)&KV[jr * 72 + c * 8] = kreg[e];
        }
        __syncthreads();                                    // B: K staged
        // ---- T14: issue V-tile + next-K global loads EARLY (hide under QK^T,
        //      barrier C, and the softmax phase) ----
        short8 vreg[4];
        for (int e = 0; e < 4; ++e) {
            int ch = t + 256 * e;
            int d = ch >> 4, c = ch & 15;
            vreg[e] = *(const short8*)&Vt[((size_t)(b * Dd + h * DHh + d)) * Tt + j0 + c * 8];
        }
        if (jt > 0) {
            for (int e = 0; e < 4; ++e) {
                int ch = t + 256 * e;
                int jr = ch >> 3, c = ch & 7;
                kreg[e] = *(const short8*)&K[((size_t)(b * Tt + j0 - 128 + jr)) * Dd + h * DHh + c * 8];
            }
        }
        {
            int ntA = 2 * wave, ntB = ntA + 1;
            floatx4 c00 = {0,0,0,0}, c01 = {0,0,0,0}, c10 = {0,0,0,0}, c11 = {0,0,0,0};
            for (int ks = 0; ks < 2; ++ks) {
                short8 b0 = *(short8*)&KV[(ntA * 16 + l16) * 72 + ks * 32 + quad * 8];
                short8 b1 = *(short8*)&KV[(ntB * 16 + l16) * 72 + ks * 32 + quad * 8];
                c00 = MFMA16(qa[0][ks], b0, c00, 0, 0, 0);
                c01 = MFMA16(qa[0][ks], b1, c01, 0, 0, 0);
                c10 = MFMA16(qa[1][ks], b0, c10, 0, 0, 0);
                c11 = MFMA16(qa[1][ks], b1, c11, 0, 0, 0);
            }
            for (int r = 0; r < 4; ++r) {
                Sld[(quad * 4 + r) * 132 + ntA * 16 + l16] = c00[r];
                Sld[(quad * 4 + r) * 132 + ntB * 16 + l16] = c01[r];
                Sld[(16 + quad * 4 + r) * 132 + ntA * 16 + l16] = c10[r];
                Sld[(16 + quad * 4 + r) * 132 + ntB * 16 + l16] = c11[r];
            }
        }
        __syncthreads();                                    // C: S ready
        {
            // read own 16 S floats (short-typed loads, bit-cast: TBAA-safe alias)
            floatx4 qv[4];
            for (int q4 = 0; q4 < 4; ++q4) {
                short8 qraw = *(short8*)&SldS[sr * 264 + ss * 32 + q4 * 8];
                __builtin_memcpy(&qv[q4], &qraw, 16);
            }
            float gt[16];
            float gs = 0.f;
            for (int e = 0; e < 16; ++e) {
                int j = j0 + ss * 16 + e;
                float qk = qv[e >> 2][e & 3];
                float g = (j <= irow) ? fsigm(qk * inv_scale) : 0.f;
                gt[e] = g;
                gs += g;
            }
            // inclusive suffix-scan of group sums across the 8 ss-groups
            float inc = gs;
            for (int d2 = 1; d2 < 8; d2 <<= 1) {
                float n = __shfl_down(inc, d2, 64);
                if ((lane & 7) + d2 < 8) inc += n;
            }
            // tile-row total lives at ss=0; broadcast within the row group
            float tileTot = __shfl(inc, lane & 56, 64);
            float base = rightAcc + (inc - gs);   // gates strictly right of group
            float run = 0.f;                      // suffix within group (exclusive)
            short8 p0, p1;
            for (int e = 15; e >= 0; --e) {
                int j = j0 + ss * 16 + e;
                float pos = base + run;           // = sum_{k > j} g_k
                run += gt[e];
                pos = fminf(fmaxf(pos, 0.f), 63.f);
                float pf = floorf(pos);
                float al = pos - pf;
                int fi = (int)pf;
                int ci = fi + 1; if (ci > 63) ci = 63;
                float qp = (1.f - al) * bf2fs(qpeB[sr * 68 + fi]) + al * bf2fs(qpeB[sr * 68 + ci]);
                float qk = qv[e >> 2][e & 3];
                float p = (j <= irow) ? __expf((qk + qp) * inv_scale) : 0.f;
                if (e < 8) p0[e] = (short)f2bf(p); else p1[e - 8] = (short)f2bf(p);
                l_acc += p;
            }
            // P overwrites the low half of this thread's OWN consumed S region
            *(short8*)&SldS[sr * 264 + ss * 32]     = p0;
            *(short8*)&SldS[sr * 264 + ss * 32 + 8] = p1;
            rightAcc += tileTot;
        }
        for (int e = 0; e < 4; ++e) {
            int ch = t + 256 * e;
            int d = ch >> 4, c = ch & 15;
            *(short8*)&KV[d * 136 + c * 8] = vreg[e];
        }
        __syncthreads();                                    // D: P + V ready
        for (int ks = 0; ks < 4; ++ks) {
            short8 a  = *(short8*)&SldS[(pv_mt * 16 + l16) * 264 + ks * 64
                                        + ((quad >> 1) << 5) + ((quad & 1) << 3)];
            short8 b0 = *(short8*)&KV[(pv_ntA * 16 + l16) * 136 + ks * 32 + quad * 8];
            short8 b1 = *(short8*)&KV[(pv_ntB * 16 + l16) * 136 + ks * 32 + quad * 8];
            o0 = MFMA16(a, b0, o0, 0, 0, 0);
            o1 = MFMA16(a, b1, o1, 0, 0, 0);
        }
    }
    float lr = l_acc;
    for (int d2 = 4; d2 >= 1; d2 >>= 1) lr += __shfl_xor(lr, d2, 64);
    if (ss == 0) lrow[sr] = lr;
    __syncthreads();
    for (int r = 0; r < 4; ++r) {
        int row = pv_mt * 16 + quad * 4 + r;
        float inv = __builtin_amdgcn_rcpf(lrow[row]);
        size_t off = ((size_t)(b * Tt + i0 + row)) * Dd + h * DHh;
        AOb[off + pv_ntA * 16 + l16] = (short)f2bf(o0[r] * inv);
        AOb[off + pv_ntB * 16 + l16] = (short)f2bf(o1[r] * inv);
    }
}

// ---------------- launch ---------------------------------------------------------
extern "C" void kernel_launch(void* const* d_in, const int* in_sizes, int n_in,
                              void* d_out, int out_size, void* d_ws, size_t ws_size,
                              hipStream_t stream)
{
    const float* x  = (const float*)d_in[0];
    const float* Wq = (const float*)d_in[1];
    const float* bq = (const float*)d_in[2];
    const float* Wk = (const float*)d_in[3];
    const float* bk = (const float*)d_in[4];
    const float* Wv = (const float*)d_in[5];
    const float* bv = (const float*)d_in[6];
    const float* Wo = (const float*)d_in[7];
    const float* bo = (const float*)d_in[8];
    const float* pe = (const float*)d_in[9];
    // d_in[10]: causal mask (j > i) — structural, unused

    short* xb   = (short*)d_ws;                         //  4 MB
    short* Wqb  = xb   + (size_t)BTt * Dd;              //  2 MB
    short* Wkb  = Wqb  + (size_t)Dd * Dd;               //  2 MB
    short* Wvb  = Wkb  + (size_t)Dd * Dd;               //  2 MB
    short* Wob  = Wvb  + (size_t)Dd * Dd;               //  2 MB
    short* Qb   = Wob  + (size_t)Dd * Dd;               //  4 MB
    short* Kb   = Qb   + (size_t)BTt * Dd;              //  4 MB
    short* Vrow = Kb   + (size_t)BTt * Dd;              //  4 MB
    short* Vtg  = Vrow + (size_t)BTt * Dd;              //  4 MB
    short* AOb  = Vtg  + (size_t)BTt * Dd;              //  4 MB

    dim3 gc(BTt * Dd / 8 / 256, 5);
    conv_bf16<<<gc, 256, 0, stream>>>(x, Wq, Wk, Wv, Wo, xb, Wqb, Wkb, Wvb, Wob);

    dim3 gq(BTt / 128, Dd / 64, 3);
    gemm_qkv<<<gq, 256, 0, stream>>>(xb, Wqb, Wkb, Wvb, bq, bk, bv, Qb, Kb, Vrow);

    dim3 gv(Tt / 64, Dd / 64, 2);
    v_transpose<<<gv, 256, 0, stream>>>(Vrow, Vtg);

    dim3 ga(32, 32, 1);   // x = h + 16*b; y = itz (CU-balanced via ITMAP)
    cope_attn<<<ga, 256, 0, stream>>>(Qb, Kb, Vtg, pe, AOb);

    dim3 go(BTt / 64, Dd / 64, 1);
    gemm_o<<<go, 256, 0, stream>>>(AOb, Wob, bo, (float*)d_out);
}